// Round 9
// baseline (130.681 us; speedup 1.0000x reference)
//
#include <hip/hip_runtime.h>

#define BB 16
#define NN 2048
#define DIN 160
#define IS 32
#define NCAT 64
#define EMBD 64
#define NCTX 2047
#define SS 66               // LDS row stride (floats) for xs[96][SS]
#define NTILE 32            // 64-col tiles per batch
#define GRID1 (BB * NTILE)  // 512
#define NPART NTILE         // partials per batch (after in-block reduce)

// ---------------------------------------------------------------------------
// K1: per-tile partial G = xq.xq^T (32x32), K = xcat.xq^T (64x32).
// Block 256 = 4 waves; wave mg covers 16 m's; lane (i4,d4) owns a 4x4 G-tile
// and 8x4 K-tile. Cross-wave LDS reduce (no fences/atomics) -> one partial
// per block, 32 per batch.
// ---------------------------------------------------------------------------
__global__ __launch_bounds__(256) void k_gram(
    const float* __restrict__ x,
    float* __restrict__ Pg, float* __restrict__ Pk)
{
    __shared__ float xs[96 * SS];        // 25,344 B, [r][m] row-major
    __shared__ float cbuf[3 * 64 * 52];  // cross-wave reduce scratch
    const int t = threadIdx.x;
    const int blk = blockIdx.x;
    const int b = blk >> 5;
    const int tile = blk & 31;
    const int n0 = tile << 6;
    const float* xb = x + (size_t)b * DIN * NN;

    for (int idx = t; idx < 96 * 32; idx += 256) {
        const int r = idx >> 5;
        const int mc = (idx & 31) << 1;
        float2 v = *(const float2*)&xb[r * NN + n0 + mc];
        if (n0 + mc + 1 == NCTX) v.y = 0.f;
        *(float2*)&xs[r * SS + mc] = v;
    }
    __syncthreads();

    const int mg = t >> 6;
    const int lane = t & 63;
    const int i4 = lane >> 3;
    const int d4 = lane & 7;
    const int i0 = i4 << 2;
    const int d0 = d4 << 2;
    const int m0 = mg << 4;

    float g[4][4], kk[8][4];
#pragma unroll
    for (int ii = 0; ii < 4; ii++)
#pragma unroll
        for (int jj = 0; jj < 4; jj++) g[ii][jj] = 0.f;
#pragma unroll
    for (int ii = 0; ii < 8; ii++)
#pragma unroll
        for (int jj = 0; jj < 4; jj++) kk[ii][jj] = 0.f;

    for (int m = m0; m < m0 + 16; m += 2) {
        float2 q[4], a[4], c[8];
#pragma unroll
        for (int j = 0; j < 4; j++) q[j] = *(const float2*)&xs[(d0 + j) * SS + m];
#pragma unroll
        for (int j = 0; j < 4; j++) a[j] = *(const float2*)&xs[(i0 + j) * SS + m];
#pragma unroll
        for (int j = 0; j < 8; j++) c[j] = *(const float2*)&xs[(32 + i4 + 8 * j) * SS + m];
#pragma unroll
        for (int ii = 0; ii < 4; ii++)
#pragma unroll
            for (int jj = 0; jj < 4; jj++)
                g[ii][jj] += a[ii].x * q[jj].x + a[ii].y * q[jj].y;
#pragma unroll
        for (int ii = 0; ii < 8; ii++)
#pragma unroll
            for (int jj = 0; jj < 4; jj++)
                kk[ii][jj] += c[ii].x * q[jj].x + c[ii].y * q[jj].y;
    }

    if (mg > 0) {
        float* p = cbuf + ((mg - 1) * 64 + lane) * 52;
#pragma unroll
        for (int ii = 0; ii < 4; ii++) *(float4*)&p[ii * 4] = *(float4*)&g[ii][0];
#pragma unroll
        for (int ii = 0; ii < 8; ii++) *(float4*)&p[16 + ii * 4] = *(float4*)&kk[ii][0];
    }
    __syncthreads();
    if (mg == 0) {
#pragma unroll
        for (int w = 0; w < 3; w++) {
            const float* p = cbuf + (w * 64 + lane) * 52;
#pragma unroll
            for (int ii = 0; ii < 4; ii++) {
                float4 v = *(const float4*)&p[ii * 4];
                g[ii][0] += v.x; g[ii][1] += v.y; g[ii][2] += v.z; g[ii][3] += v.w;
            }
#pragma unroll
            for (int ii = 0; ii < 8; ii++) {
                float4 v = *(const float4*)&p[16 + ii * 4];
                kk[ii][0] += v.x; kk[ii][1] += v.y; kk[ii][2] += v.z; kk[ii][3] += v.w;
            }
        }
        float* pg = Pg + (size_t)blk * 1024;
#pragma unroll
        for (int ii = 0; ii < 4; ii++)
            *(float4*)&pg[(i0 + ii) * 32 + d0] = *(float4*)&g[ii][0];
        float* pk = Pk + (size_t)blk * 2048;
#pragma unroll
        for (int ii = 0; ii < 8; ii++)
            *(float4*)&pk[(i4 + 8 * ii) * 32 + d0] = *(float4*)&kk[ii][0];
    }
}

// ---------------------------------------------------------------------------
// K2: per (b, 128-col tile): reduce 32 partials -> G,K; chain -> U; epilogue
// logits = emb^T.x_tail + U.xq; softmax. LDS union: {G,K,C,W} overlays the
// softmax-exchange buffer (never live together) -> 44 KB -> 3 blocks/CU.
// ---------------------------------------------------------------------------
__global__ __launch_bounds__(256) void k_out(
    const float* __restrict__ x, const float* __restrict__ Pg,
    const float* __restrict__ Pk, const float* __restrict__ alpha,
    const float* __restrict__ kp, const float* __restrict__ emb,
    const float* __restrict__ Mm, float* __restrict__ out)
{
    __shared__ float un[8704];      // union: G(1152)+K(2304)+C(2304)+W(2304)=8064 | lg_s 128*68=8704
    __shared__ float U_s[64][36];   // T-scratch, then final U
    float (*G_s)[36] = (float(*)[36])un;
    float (*K_s)[36] = (float(*)[36])(un + 1152);
    float (*C_s)[36] = (float(*)[36])(un + 3456);
    float (*W_s)[36] = (float(*)[36])(un + 5760);
    float (*lg_s)[68] = (float(*)[68])un;

    const int t = threadIdx.x;
    const int blk = blockIdx.x;
    const int b = blk >> 4;
    const int tile = blk & 15;
    const float* xb = x + (size_t)b * DIN * NN;

    // epilogue thread map (also used for the xq preload)
    const int h = t >> 7;
    const int nl = t & 127;
    const int n = (tile << 7) + nl;
    const int c0 = h << 5;

    // ---- preload xq column into regs: loads in flight during reduce+chain ----
    float xq[IS];
#pragma unroll
    for (int d = 0; d < IS; d++) xq[d] = xb[d * NN + n];

    // ---- reduce partials (L2-hot) ----
    {
        const int row = t >> 3, col = (t & 7) << 2;
        float4 s = {0, 0, 0, 0};
        const float* base = Pg + (size_t)b * NPART * 1024 + row * 32 + col;
#pragma unroll 8
        for (int p = 0; p < NPART; p++) {
            float4 v = *(const float4*)(base + (size_t)p * 1024);
            s.x += v.x; s.y += v.y; s.z += v.z; s.w += v.w;
        }
        *(float4*)&G_s[row][col] = s;
    }
    {
        const int row0 = t >> 2, col = (t & 3) << 3;
        const float* base = Pk + (size_t)b * NPART * 2048 + row0 * 32 + col;
        float4 s0 = {0, 0, 0, 0}, s1 = {0, 0, 0, 0};
#pragma unroll 8
        for (int p = 0; p < NPART; p++) {
            float4 v0 = *(const float4*)(base + (size_t)p * 2048);
            float4 v1 = *(const float4*)(base + (size_t)p * 2048 + 4);
            s0.x += v0.x; s0.y += v0.y; s0.z += v0.z; s0.w += v0.w;
            s1.x += v1.x; s1.y += v1.y; s1.z += v1.z; s1.w += v1.w;
        }
        *(float4*)&K_s[row0][col] = s0;
        *(float4*)&K_s[row0][col + 4] = s1;
    }
    __syncthreads();

    // ---- chain: C0 = emb.K; l: W += f*C; C += M.(f*C.G) (l<2) ----
    const int r  = t >> 2;
    const int dd = (t & 3) << 3;
    {
        const float* er = emb + r * EMBD;
        float acc[8];
#pragma unroll
        for (int j = 0; j < 8; j++) acc[j] = 0.f;
        for (int c = 0; c < 64; c++) {
            const float e = er[c];
#pragma unroll
            for (int j = 0; j < 8; j++) acc[j] += e * K_s[c][dd + j];
        }
#pragma unroll
        for (int j = 0; j < 8; j++) C_s[r][dd + j] = acc[j];
    }
    __syncthreads();

    const float scale = kp[0] * (1.f / (float)NCTX);
    for (int l = 0; l < 3; l++) {
        const float f = scale * alpha[l * EMBD + r];
#pragma unroll
        for (int j = 0; j < 8; j++) {
            const float w = f * C_s[r][dd + j];
            if (l == 0) W_s[r][dd + j] = w; else W_s[r][dd + j] += w;
        }
        if (l < 2) {
            float tacc[8];
#pragma unroll
            for (int j = 0; j < 8; j++) tacc[j] = 0.f;
            for (int d = 0; d < 32; d++) {
                const float cv = C_s[r][d];
#pragma unroll
                for (int j = 0; j < 8; j++) tacc[j] += cv * G_s[d][dd + j];
            }
#pragma unroll
            for (int j = 0; j < 8; j++) U_s[r][dd + j] = f * tacc[j];  // U_s as T scratch
            __syncthreads();
            const float* Mr = Mm + r * EMBD;
            float uacc[8];
#pragma unroll
            for (int j = 0; j < 8; j++) uacc[j] = 0.f;
            for (int jj = 0; jj < 64; jj++) {
                const float mv = Mr[jj];
#pragma unroll
                for (int j = 0; j < 8; j++) uacc[j] += mv * U_s[jj][dd + j];
            }
#pragma unroll
            for (int j = 0; j < 8; j++) C_s[r][dd + j] += uacc[j];
            __syncthreads();
        }
    }
    __syncthreads();

    // U[c][d] = sum_e emb[e][c] * W[e][d]  (c = r) -> U_s
    {
        float acc[8];
#pragma unroll
        for (int j = 0; j < 8; j++) acc[j] = 0.f;
        for (int e = 0; e < 64; e++) {
            const float ev = emb[e * EMBD + r];
#pragma unroll
            for (int j = 0; j < 8; j++) acc[j] += ev * W_s[e][dd + j];
        }
#pragma unroll
        for (int j = 0; j < 8; j++) U_s[r][dd + j] = acc[j];
    }
    __syncthreads();  // chain scratch dead; union becomes lg_s

    // ---- epilogue ----
    float lg[32];
#pragma unroll 4
    for (int cl = 0; cl < 32; cl++) {
        const float* Ur = &U_s[c0 + cl][0];  // wave-uniform LDS row -> broadcast
        float s = 0.f;
#pragma unroll
        for (int k = 0; k < 8; k++) {
            float4 u = *(const float4*)&Ur[4 * k];
            s += u.x * xq[4*k] + u.y * xq[4*k+1] + u.z * xq[4*k+2] + u.w * xq[4*k+3];
        }
        lg[cl] = s;
    }
    for (int e = 0; e < 64; e++) {
        const float tv = xb[(IS + NCAT + e) * NN + n];
        const float* er = emb + e * EMBD + c0;  // wave-uniform -> s_load
#pragma unroll
        for (int cl = 0; cl < 32; cl++) lg[cl] += er[cl] * tv;
    }

    const size_t base = ((size_t)b * NN + n) * (size_t)NCAT;
    float* lo = out + base + c0;
#pragma unroll
    for (int k = 0; k < 8; k++) {
        float4 v = {lg[4*k], lg[4*k+1], lg[4*k+2], lg[4*k+3]};
        *(float4*)&lo[4*k] = v;
        *(float4*)&lg_s[nl][c0 + 4*k] = v;
    }
    __syncthreads();

    const int o0 = (1 - h) << 5;
    float mx = lg[0];
#pragma unroll
    for (int cl = 1; cl < 32; cl++) mx = fmaxf(mx, lg[cl]);
    float og[32];
#pragma unroll
    for (int k = 0; k < 8; k++) {
        float4 v = *(const float4*)&lg_s[nl][o0 + 4*k];
        og[4*k] = v.x; og[4*k+1] = v.y; og[4*k+2] = v.z; og[4*k+3] = v.w;
    }
#pragma unroll
    for (int cl = 0; cl < 32; cl++) mx = fmaxf(mx, og[cl]);

    float sum = 0.f;
#pragma unroll
    for (int cl = 0; cl < 32; cl++) {
        lg[cl] = __expf(lg[cl] - mx);
        sum += lg[cl];
    }
#pragma unroll
    for (int cl = 0; cl < 32; cl++) sum += __expf(og[cl] - mx);

    const float inv = 1.f / sum;
    float* po = out + (size_t)BB * NN * NCAT + base + c0;
#pragma unroll
    for (int k = 0; k < 8; k++) {
        float4 v = {lg[4*k]*inv, lg[4*k+1]*inv, lg[4*k+2]*inv, lg[4*k+3]*inv};
        *(float4*)&po[4*k] = v;
    }
}

extern "C" void kernel_launch(void* const* d_in, const int* in_sizes, int n_in,
                              void* d_out, int out_size, void* d_ws, size_t ws_size,
                              hipStream_t stream) {
    const float* x     = (const float*)d_in[0];
    const float* alpha = (const float*)d_in[1];
    const float* kp    = (const float*)d_in[2];
    const float* emb   = (const float*)d_in[3];
    const float* Mmat  = (const float*)d_in[4];
    float* out = (float*)d_out;

    float* Pg = (float*)d_ws;                 // 512 * 1024 floats
    float* Pk = Pg + (size_t)GRID1 * 1024;    // 512 * 2048 floats

    k_gram<<<GRID1, 256, 0, stream>>>(x, Pg, Pk);
    k_out <<<256,   256, 0, stream>>>(x, Pg, Pk, alpha, kp, emb, Mmat, out);
}